// Round 18
// baseline (461.597 us; speedup 1.0000x reference)
//
#include <hip/hip_runtime.h>
#include <hip/hip_bf16.h>

#define H 128
#define NN 2048
#define BB 2
#define EPSF 1e-5f
#define NPER 4

typedef __bf16 bf16;
typedef bf16 bf16x8 __attribute__((ext_vector_type(8)));
typedef bf16 bf16x4 __attribute__((ext_vector_type(4)));
typedef float f32x4 __attribute__((ext_vector_type(4)));
typedef float f32x2 __attribute__((ext_vector_type(2)));

// ---- ws layout ----
// bf16 elems [0, 311296): weights
//   Wm1T full [128][512] @ 0      (segs: self | hE-fold (k-PHI) | hV_nb | hVa_nb)
//   W2T   @ 65536, W3T @ 81920   (k-dim PHI)
//   W11T full [128][384] @ 98304  (segs: self | hE (k-PHI) | hV2_nb)
//   W12T  @ 147456, W13T @ 163840 (k-dim PHI)
//   WinT [512][128] @ 180224, WoutT [128][512] @ 245760
// phi(c) = (c&~31) + (c&15)*2 + ((c>>4)&1)
// U1/V1/U2/V2 tables stored PHI-PACKED.
#define U1_F     155648
#define U2_F     679936
#define HVMID_F  1204224
#define V2_F     1990656
#define V1_F     2252800
#define HVMID_B  3457024

__device__ __forceinline__ float gelu_f(float x) {
    float u = x * x;
    float p = __builtin_fmaf(u, 0.044715f, 1.0f);
    float w = x * p;
    float e = __builtin_amdgcn_exp2f(w * -2.3022083f);
    return x * __builtin_amdgcn_rcpf(1.0f + e);
}

#define MFMA16(a, b, c) __builtin_amdgcn_mfma_f32_16x16x32_bf16((a), (b), (c), 0, 0, 0)

#define GEMM_PIPE(U, A_EXPR, B0p, B1p, ACC)                                       \
    {                                                                             \
        bf16x8 bq0[3], bq1[3];                                                    \
        _Pragma("unroll")                                                         \
        for (int j = 0; j < 3 && j < (U); ++j) {                                  \
            bq0[j] = *(const bf16x8*)((B0p) + j * 32);                            \
            bq1[j] = *(const bf16x8*)((B1p) + j * 32);                            \
        }                                                                         \
        bf16x8 afc[3], afn[3];                                                    \
        _Pragma("unroll")                                                         \
        for (int rt = 0; rt < 3; ++rt) { const int u = 0; afc[rt] = (A_EXPR); }   \
        _Pragma("unroll")                                                         \
        for (int uu = 0; uu < (U); ++uu) {                                        \
            if (uu + 1 < (U)) {                                                   \
                _Pragma("unroll")                                                 \
                for (int rt = 0; rt < 3; ++rt) { const int u = uu + 1; afn[rt] = (A_EXPR); } \
            }                                                                     \
            __builtin_amdgcn_s_setprio(1);                                        \
            _Pragma("unroll")                                                     \
            for (int rt = 0; rt < 3; ++rt) {                                      \
                ACC[rt][0] = MFMA16(afc[rt], bq0[uu % 3], ACC[rt][0]);            \
                ACC[rt][1] = MFMA16(afc[rt], bq1[uu % 3], ACC[rt][1]);            \
            }                                                                     \
            __builtin_amdgcn_s_setprio(0);                                        \
            if (uu + 3 < (U)) {                                                   \
                bq0[uu % 3] = *(const bf16x8*)((B0p) + (uu + 3) * 32);            \
                bq1[uu % 3] = *(const bf16x8*)((B1p) + (uu + 3) * 32);            \
            }                                                                     \
            _Pragma("unroll")                                                     \
            for (int rt = 0; rt < 3; ++rt) afc[rt] = afn[rt];                     \
        }                                                                         \
    }

#define PACK_STORE(DST, ROW, PCOL, V0, V1)                                        \
    {                                                                             \
        union { bf16 h[2]; unsigned u; } pk_;                                     \
        pk_.h[0] = (V0); pk_.h[1] = (V1);                                         \
        *(unsigned*)&DST[ROW][PCOL] = pk_.u;                                      \
    }

// ---------------- weight prep ----------------
__global__ void prep_weights(const float* __restrict__ W1, const float* __restrict__ W2,
                             const float* __restrict__ W3, const float* __restrict__ W11,
                             const float* __restrict__ W12, const float* __restrict__ W13,
                             const float* __restrict__ Win, const float* __restrict__ Wout,
                             bf16* __restrict__ ws)
{
    int i = blockIdx.x * 256 + threadIdx.x;
    float v;
    if (i < 65536) {
        int c = i >> 9, k = i & 511, s = k >> 7, k0 = k & 127;
        if (s == 0)      v = W1[k0 * H + c];
        else if (s == 1) {
            int klog = (k0 & ~31) + ((k0 & 1) << 4) + ((k0 & 31) >> 1);
            v = W1[(128 + klog) * H + c] + W1[(384 + klog) * H + c];
        }
        else if (s == 2) v = W1[(256 + k0) * H + c];
        else             v = W1[(512 + k0) * H + c];
    } else if (i < 81920)  { int j = i - 65536;  int c = j >> 7, p = j & 127;
                             int k = (p & ~31) + ((p & 1) << 4) + ((p & 31) >> 1);
                             v = W2[k * H + c]; }
    else if (i < 98304)    { int j = i - 81920;  int c = j >> 7, p = j & 127;
                             int k = (p & ~31) + ((p & 1) << 4) + ((p & 31) >> 1);
                             v = W3[k * H + c]; }
    else if (i < 147456)   { int j = i - 98304;  int c = j / 384, k = j - c * 384;
                             if (k >= 128 && k < 256) {
                                 int p = k - 128;
                                 int klog = (p & ~31) + ((p & 1) << 4) + ((p & 31) >> 1);
                                 v = W11[(128 + klog) * H + c];
                             } else {
                                 v = W11[k * H + c];
                             } }
    else if (i < 163840)   { int j = i - 147456; int c = j >> 7, p = j & 127;
                             int k = (p & ~31) + ((p & 1) << 4) + ((p & 31) >> 1);
                             v = W12[k * H + c]; }
    else if (i < 180224)   { int j = i - 163840; int c = j >> 7, p = j & 127;
                             int k = (p & ~31) + ((p & 1) << 4) + ((p & 31) >> 1);
                             v = W13[k * H + c]; }
    else if (i < 245760)   { int j = i - 180224; int jj = j >> 7, k = j & 127; v = Win[k * 512 + jj]; }
    else                   { int j = i - 245760; int c = j >> 9, k = j & 511; v = Wout[k * H + c]; }
    ws[i] = (bf16)v;
}

// ---------------- u1: U1 = hV@W1a + b1 ; V1 = hV@W1c + hVa@W1d (phi-packed stores) ----------------
__global__ __launch_bounds__(512) void u1_kernel(
    const float* __restrict__ hV, const float* __restrict__ hVa,
    const float* __restrict__ b1, const bf16* __restrict__ ws, float* __restrict__ wsf)
{
    int n0 = blockIdx.x * 128;
    int t = threadIdx.x, w = t >> 6, l = t & 63, l16 = l & 15, lg = l >> 4;
    int wm = w >> 2, wn = w & 3;
    __shared__ __align__(16) bf16 sA[128][136];
    __shared__ __align__(16) bf16 sB[128][136];

    #pragma unroll
    for (int i = 0; i < 8; ++i) {
        int idx = t + i * 512;
        int row = idx >> 5, c4 = (idx & 31) << 2;
        f32x4 v = *(const f32x4*)(hV + (size_t)(n0 + row) * H + c4);
        bf16x4 o; o[0] = (bf16)v[0]; o[1] = (bf16)v[1]; o[2] = (bf16)v[2]; o[3] = (bf16)v[3];
        *(bf16x4*)(&sA[row][c4]) = o;
        f32x4 va = *(const f32x4*)(hVa + (size_t)(n0 + row) * H + c4);
        bf16x4 oa; oa[0] = (bf16)va[0]; oa[1] = (bf16)va[1]; oa[2] = (bf16)va[2]; oa[3] = (bf16)va[3];
        *(bf16x4*)(&sB[row][c4]) = oa;
    }
    __syncthreads();

    f32x4 accU[4][2], accV[4][2];
    #pragma unroll
    for (int rt = 0; rt < 4; ++rt)
        #pragma unroll
        for (int c2 = 0; c2 < 2; ++c2) {
            accU[rt][c2] = (f32x4){0.f, 0.f, 0.f, 0.f};
            accV[rt][c2] = (f32x4){0.f, 0.f, 0.f, 0.f};
        }
    #pragma unroll
    for (int kk = 0; kk < 4; ++kk) {
        bf16x8 af[4];
        #pragma unroll
        for (int rt = 0; rt < 4; ++rt)
            af[rt] = *(const bf16x8*)(&sA[wm * 64 + rt * 16 + l16][kk * 32 + lg * 8]);
        #pragma unroll
        for (int c2 = 0; c2 < 2; ++c2) {
            int c = wn * 32 + c2 * 16 + l16;
            bf16x8 bU = *(const bf16x8*)(&ws[(size_t)c * 512 + kk * 32 + lg * 8]);
            bf16x8 bV = *(const bf16x8*)(&ws[(size_t)c * 512 + 256 + kk * 32 + lg * 8]);
            #pragma unroll
            for (int rt = 0; rt < 4; ++rt) {
                accU[rt][c2] = MFMA16(af[rt], bU, accU[rt][c2]);
                accV[rt][c2] = MFMA16(af[rt], bV, accV[rt][c2]);
            }
        }
    }
    #pragma unroll
    for (int kk = 0; kk < 4; ++kk) {
        bf16x8 af[4];
        #pragma unroll
        for (int rt = 0; rt < 4; ++rt)
            af[rt] = *(const bf16x8*)(&sB[wm * 64 + rt * 16 + l16][kk * 32 + lg * 8]);
        #pragma unroll
        for (int c2 = 0; c2 < 2; ++c2) {
            int c = wn * 32 + c2 * 16 + l16;
            bf16x8 bV = *(const bf16x8*)(&ws[(size_t)c * 512 + 384 + kk * 32 + lg * 8]);
            #pragma unroll
            for (int rt = 0; rt < 4; ++rt)
                accV[rt][c2] = MFMA16(af[rt], bV, accV[rt][c2]);
        }
    }
    {
        int col0 = wn * 32 + l16, col1 = col0 + 16;
        int pcol = wn * 32 + l16 * 2;
        float bb0 = b1[col0], bb1 = b1[col1];
        #pragma unroll
        for (int rt = 0; rt < 4; ++rt)
            #pragma unroll
            for (int i = 0; i < 4; ++i) {
                int row = wm * 64 + rt * 16 + lg * 4 + i;
                f32x2 su; su[0] = accU[rt][0][i] + bb0; su[1] = accU[rt][1][i] + bb1;
                *(f32x2*)(wsf + U1_F + (size_t)(n0 + row) * H + pcol) = su;
                f32x2 sv; sv[0] = accV[rt][0][i]; sv[1] = accV[rt][1][i];
                *(f32x2*)(wsf + V1_F + (size_t)(n0 + row) * H + pcol) = sv;
            }
    }
}

// ---------------- node message: persistent, NPER nodes/block, double-buffered stage ----------------
__global__ __launch_bounds__(256, 3) void node_msg_kernel(
    const float* __restrict__ hV, const float* __restrict__ hE,
    const float* __restrict__ b2, const float* __restrict__ b3,
    const float* __restrict__ g1, const float* __restrict__ be1,
    const float* __restrict__ maskA, const int* __restrict__ Eidx,
    bf16* __restrict__ ws, float* __restrict__ wsf)
{
    // 40192 B: sAbuf0 @0 [48][136], sAbuf1 @13056, sH2 @26112, sDH @39168 (512 B)
    __shared__ __align__(16) char smem[40192];
    bf16 (*sH2)[136] = (bf16(*)[136])(smem + 26112);
    float* sDH = (float*)(smem + 39168);

    int t = threadIdx.x, w = t >> 6, l = t & 63, l16 = l & 15, lg = l >> 4;
    int col0 = w * 32 + l16, col1 = col0 + 16;
    int pcol = w * 32 + l16 * 2;
    float b2v0 = b2[col0], b2v1 = b2[col1];
    float b3v0 = b3[col0], b3v1 = b3[col1];

    int n0b = blockIdx.x * NPER, b = n0b >> 11;

    // ---- prologue: node n0b scalars + stage into buf0 ----
    f32x2 u1p = *(const f32x2*)(wsf + U1_F + (size_t)n0b * H + pcol);
    float v1a[3][4], v1b[3][4];
    #pragma unroll
    for (int rt = 0; rt < 3; ++rt)
        #pragma unroll
        for (int i = 0; i < 4; ++i) {
            int row = rt * 16 + lg * 4 + i;
            int nbr = Eidx[n0b * 48 + row];
            f32x2 vv = *(const f32x2*)(wsf + V1_F + ((size_t)b * NN + nbr) * H + pcol);
            v1a[rt][i] = vv[0]; v1b[rt][i] = vv[1];
        }
    {
        bf16 (*sA0)[136] = (bf16(*)[136])smem;
        #pragma unroll
        for (int i = 0; i < 6; ++i) {
            int idx = t + i * 256, row = idx >> 5, q = idx & 31;
            int c0 = (q >> 3) * 32 + (q & 7) * 2;
            const float* hp = hE + ((size_t)n0b * 48 + row) * H + c0;
            f32x2 a = *(const f32x2*)hp, c = *(const f32x2*)(hp + 16);
            bf16x4 o; o[0] = (bf16)a[0]; o[1] = (bf16)c[0]; o[2] = (bf16)a[1]; o[3] = (bf16)c[1];
            *(bf16x4*)(&sA0[row][q * 4]) = o;
        }
    }
    __syncthreads();

    int cur = 0;
    #pragma unroll 1
    for (int it = 0; it < NPER; ++it) {
        int n = n0b + it;
        bf16 (*sA)[136]  = (bf16(*)[136])(smem + cur * 13056);
        bf16 (*sAn)[136] = (bf16(*)[136])(smem + (cur ^ 1) * 13056);

        // issue next node's hE loads (in flight across G1)
        f32x2 nga[6], ngc[6];
        if (it + 1 < NPER) {
            #pragma unroll
            for (int i = 0; i < 6; ++i) {
                int idx = t + i * 256, row = idx >> 5, q = idx & 31;
                int c0 = (q >> 3) * 32 + (q & 7) * 2;
                const float* hp = hE + ((size_t)(n + 1) * 48 + row) * H + c0;
                nga[i] = *(const f32x2*)hp; ngc[i] = *(const f32x2*)(hp + 16);
            }
        }

        // ---- G1: 48x128 @ 128x128 (hE-fold seg, k-phi) ----
        f32x4 acc[3][2];
        #pragma unroll
        for (int rt = 0; rt < 3; ++rt)
            #pragma unroll
            for (int c2 = 0; c2 < 2; ++c2) acc[rt][c2] = (f32x4){0.f, 0.f, 0.f, 0.f};
        {
            const bf16* B0 = ws + (size_t)col0 * 512 + 128 + lg * 8;
            const bf16* B1 = ws + (size_t)col1 * 512 + 128 + lg * 8;
            GEMM_PIPE(4, (*(const bf16x8*)(&sA[rt * 16 + l16][u * 32 + lg * 8])), B0, B1, acc)
        }
        __syncthreads();   // all sA reads done -> overlay safe

        // epi1: gelu(acc + U1 + V1[nbr]) -> sH1 (= sA region, packed)
        #pragma unroll
        for (int rt = 0; rt < 3; ++rt)
            #pragma unroll
            for (int i = 0; i < 4; ++i) {
                int row = rt * 16 + lg * 4 + i;
                bf16 v0 = (bf16)gelu_f(acc[rt][0][i] + u1p[0] + v1a[rt][i]);
                bf16 v1 = (bf16)gelu_f(acc[rt][1][i] + u1p[1] + v1b[rt][i]);
                PACK_STORE(sA, row, pcol, v0, v1)
            }

        // write next stage -> sAn (loads already landed under G1)
        if (it + 1 < NPER) {
            #pragma unroll
            for (int i = 0; i < 6; ++i) {
                int idx = t + i * 256, row = idx >> 5, q = idx & 31;
                bf16x4 o; o[0] = (bf16)nga[i][0]; o[1] = (bf16)ngc[i][0];
                o[2] = (bf16)nga[i][1]; o[3] = (bf16)ngc[i][1];
                *(bf16x4*)(&sAn[row][q * 4]) = o;
            }
        }

        // current mask + next scalars (latency covered by G2/G3)
        float mk[3][4];
        #pragma unroll
        for (int rt = 0; rt < 3; ++rt)
            #pragma unroll
            for (int i = 0; i < 4; ++i)
                mk[rt][i] = maskA[n * 48 + rt * 16 + lg * 4 + i];
        f32x2 u1pn; float v1an[3][4], v1bn[3][4];
        if (it + 1 < NPER) {
            u1pn = *(const f32x2*)(wsf + U1_F + (size_t)(n + 1) * H + pcol);
            #pragma unroll
            for (int rt = 0; rt < 3; ++rt)
                #pragma unroll
                for (int i = 0; i < 4; ++i) {
                    int row = rt * 16 + lg * 4 + i;
                    int nbr = Eidx[(n + 1) * 48 + row];
                    f32x2 vv = *(const f32x2*)(wsf + V1_F + ((size_t)b * NN + nbr) * H + pcol);
                    v1an[rt][i] = vv[0]; v1bn[rt][i] = vv[1];
                }
        }
        __syncthreads();   // sH1 + sAn visible

        // ---- G2 ----
        f32x4 a2[3][2];
        #pragma unroll
        for (int rt = 0; rt < 3; ++rt)
            #pragma unroll
            for (int c2 = 0; c2 < 2; ++c2) a2[rt][c2] = (f32x4){0.f, 0.f, 0.f, 0.f};
        {
            const bf16* B0 = ws + 65536 + (size_t)col0 * 128 + lg * 8;
            const bf16* B1 = ws + 65536 + (size_t)col1 * 128 + lg * 8;
            GEMM_PIPE(4, (*(const bf16x8*)(&sA[rt * 16 + l16][u * 32 + lg * 8])), B0, B1, a2)
        }
        // epi2 -> sH2
        #pragma unroll
        for (int rt = 0; rt < 3; ++rt)
            #pragma unroll
            for (int i = 0; i < 4; ++i) {
                int row = rt * 16 + lg * 4 + i;
                bf16 v0 = (bf16)gelu_f(a2[rt][0][i] + b2v0);
                bf16 v1 = (bf16)gelu_f(a2[rt][1][i] + b2v1);
                PACK_STORE(sH2, row, pcol, v0, v1)
            }
        __syncthreads();

        // ---- G3 ----
        f32x4 a3[3][2];
        #pragma unroll
        for (int rt = 0; rt < 3; ++rt)
            #pragma unroll
            for (int c2 = 0; c2 < 2; ++c2) a3[rt][c2] = (f32x4){0.f, 0.f, 0.f, 0.f};
        {
            const bf16* B0 = ws + 81920 + (size_t)col0 * 128 + lg * 8;
            const bf16* B1 = ws + 81920 + (size_t)col1 * 128 + lg * 8;
            GEMM_PIPE(4, (*(const bf16x8*)(&sH2[rt * 16 + l16][u * 32 + lg * 8])), B0, B1, a3)
        }
        float r0s = 0.f, r1s = 0.f;
        #pragma unroll
        for (int rt = 0; rt < 3; ++rt)
            #pragma unroll
            for (int i = 0; i < 4; ++i) {
                r0s += (a3[rt][0][i] + b3v0) * mk[rt][i];
                r1s += (a3[rt][1][i] + b3v1) * mk[rt][i];
            }
        r0s += __shfl_xor(r0s, 16); r0s += __shfl_xor(r0s, 32);
        r1s += __shfl_xor(r1s, 16); r1s += __shfl_xor(r1s, 32);
        if (l < 16) { sDH[w * 32 + l] = r0s; sDH[w * 32 + 16 + l] = r1s; }
        __syncthreads();

        // LN1 for node n
        if (w == 0) {
            float x0 = hV[(size_t)n * H + l] + sDH[l] * (1.0f / 30.0f);
            float x1 = hV[(size_t)n * H + l + 64] + sDH[l + 64] * (1.0f / 30.0f);
            float s1 = x0 + x1, s2 = x0 * x0 + x1 * x1;
            #pragma unroll
            for (int off = 32; off; off >>= 1) { s1 += __shfl_xor(s1, off); s2 += __shfl_xor(s2, off); }
            float m = s1 * (1.f / 128.f);
            float rs = rsqrtf(s2 * (1.f / 128.f) - m * m + EPSF);
            float y0 = (x0 - m) * rs * g1[l] + be1[l];
            float y1 = (x1 - m) * rs * g1[l + 64] + be1[l + 64];
            wsf[HVMID_F + (size_t)n * H + l] = y0;
            wsf[HVMID_F + (size_t)n * H + l + 64] = y1;
            ws[HVMID_B + (size_t)n * H + l] = (bf16)y0;
            ws[HVMID_B + (size_t)n * H + l + 64] = (bf16)y1;
        }

        // rotate per-node state
        if (it + 1 < NPER) {
            u1p = u1pn;
            #pragma unroll
            for (int rt = 0; rt < 3; ++rt)
                #pragma unroll
                for (int i = 0; i < 4; ++i) { v1a[rt][i] = v1an[rt][i]; v1b[rt][i] = v1bn[rt][i]; }
        }
        cur ^= 1;
        __syncthreads();   // conservative loop-boundary barrier
    }
}

// ---------------- FFN batched: 32 nodes/block, + LN2 + maskV + U2/V2 (phi stores) ----------------
__global__ __launch_bounds__(512) void ffn_kernel(
    const float* __restrict__ b_in, const float* __restrict__ b_out,
    const float* __restrict__ b11, const float* __restrict__ g2,
    const float* __restrict__ be2, const float* __restrict__ maskV,
    bf16* __restrict__ ws, float* __restrict__ wsf, float* __restrict__ outV)
{
    int n0 = blockIdx.x * 32;
    int t = threadIdx.x, w = t >> 6, l = t & 63, l16 = l & 15, lg = l >> 4;

    __shared__ __align__(16) char smem[8704 + 33280];
    bf16 (*sA)[136]  = (bf16(*)[136])(smem);
    bf16 (*sFF)[520] = (bf16(*)[520])(smem + 8704);
    float (*sX)[132] = (float(*)[132])(smem + 8704);

    {
        int row = t >> 4, c8 = (t & 15) << 3;
        *(bf16x8*)(&sA[row][c8]) = *(const bf16x8*)(ws + HVMID_B + (size_t)(n0 + row) * H + c8);
    }
    __syncthreads();

    f32x4 a1[2][4];
    #pragma unroll
    for (int rt = 0; rt < 2; ++rt)
        #pragma unroll
        for (int ct = 0; ct < 4; ++ct) a1[rt][ct] = (f32x4){0.f, 0.f, 0.f, 0.f};
    #pragma unroll
    for (int kk = 0; kk < 4; ++kk) {
        bf16x8 af[2];
        #pragma unroll
        for (int rt = 0; rt < 2; ++rt)
            af[rt] = *(const bf16x8*)(&sA[rt * 16 + l16][kk * 32 + lg * 8]);
        #pragma unroll
        for (int ct = 0; ct < 4; ++ct) {
            int c = w * 64 + ct * 16 + l16;
            bf16x8 bfr = *(const bf16x8*)(&ws[180224 + (size_t)c * 128 + kk * 32 + lg * 8]);
            #pragma unroll
            for (int rt = 0; rt < 2; ++rt)
                a1[rt][ct] = MFMA16(af[rt], bfr, a1[rt][ct]);
        }
    }
    #pragma unroll
    for (int ct = 0; ct < 4; ++ct) {
        int c = w * 64 + ct * 16 + l16;
        float bb = b_in[c];
        #pragma unroll
        for (int rt = 0; rt < 2; ++rt)
            #pragma unroll
            for (int i = 0; i < 4; ++i) {
                int row = rt * 16 + lg * 4 + i;
                sFF[row][c] = (bf16)gelu_f(a1[rt][ct][i] + bb);
            }
    }
    __syncthreads();

    f32x4 a2[2];
    a2[0] = (f32x4){0.f, 0.f, 0.f, 0.f}; a2[1] = (f32x4){0.f, 0.f, 0.f, 0.f};
    int cc = w * 16 + l16;
    #pragma unroll
    for (int kk = 0; kk < 16; ++kk) {
        bf16x8 af[2];
        #pragma unroll
        for (int rt = 0; rt < 2; ++rt)
            af[rt] = *(const bf16x8*)(&sFF[rt * 16 + l16][kk * 32 + lg * 8]);
        bf16x8 bfr = *(const bf16x8*)(&ws[245760 + (size_t)cc * 512 + kk * 32 + lg * 8]);
        #pragma unroll
        for (int rt = 0; rt < 2; ++rt)
            a2[rt] = MFMA16(af[rt], bfr, a2[rt]);
    }
    __syncthreads();
    {
        float bb = b_out[cc];
        #pragma unroll
        for (int rt = 0; rt < 2; ++rt)
            #pragma unroll
            for (int i = 0; i < 4; ++i) {
                int row = rt * 16 + lg * 4 + i;
                sX[row][cc] = a2[rt][i] + bb + wsf[HVMID_F + (size_t)(n0 + row) * H + cc];
            }
    }
    __syncthreads();

    if (t < 128) {
        int row = t >> 2, q = t & 3;
        float xr[32], s1 = 0.f, s2 = 0.f;
        #pragma unroll
        for (int j = 0; j < 32; ++j) {
            float x = sX[row][q * 32 + j];
            xr[j] = x; s1 += x; s2 += x * x;
        }
        s1 += __shfl_xor(s1, 1); s1 += __shfl_xor(s1, 2);
        s2 += __shfl_xor(s2, 1); s2 += __shfl_xor(s2, 2);
        float m = s1 * (1.f / 128.f);
        float vv = s2 * (1.f / 128.f) - m * m;
        float rs = rsqrtf(vv + EPSF);
        float mv = maskV[n0 + row];
        #pragma unroll
        for (int j = 0; j < 32; ++j) {
            int c = q * 32 + j;
            float y = ((xr[j] - m) * rs * g2[c] + be2[c]) * mv;
            outV[(size_t)(n0 + row) * H + c] = y;
            sA[row][c] = (bf16)y;
        }
    }
    __syncthreads();

    // U2 = hV2 @ W11a + b11 ; V2 = hV2 @ W11c   (stored phi-packed)
    f32x4 a3[2], a4[2];
    a3[0] = (f32x4){0.f, 0.f, 0.f, 0.f}; a3[1] = (f32x4){0.f, 0.f, 0.f, 0.f};
    a4[0] = (f32x4){0.f, 0.f, 0.f, 0.f}; a4[1] = (f32x4){0.f, 0.f, 0.f, 0.f};
    #pragma unroll
    for (int kk = 0; kk < 4; ++kk) {
        bf16x8 af[2];
        #pragma unroll
        for (int rt = 0; rt < 2; ++rt)
            af[rt] = *(const bf16x8*)(&sA[rt * 16 + l16][kk * 32 + lg * 8]);
        bf16x8 bU = *(const bf16x8*)(&ws[98304 + (size_t)cc * 384 + kk * 32 + lg * 8]);
        bf16x8 bV = *(const bf16x8*)(&ws[98304 + (size_t)cc * 384 + 256 + kk * 32 + lg * 8]);
        #pragma unroll
        for (int rt = 0; rt < 2; ++rt) {
            a3[rt] = MFMA16(af[rt], bU, a3[rt]);
            a4[rt] = MFMA16(af[rt], bV, a4[rt]);
        }
    }
    {
        float bb = b11[cc];
        int pc = (cc & ~31) + l16 * 2 + ((cc >> 4) & 1);   // phi(cc)
        #pragma unroll
        for (int rt = 0; rt < 2; ++rt)
            #pragma unroll
            for (int i = 0; i < 4; ++i) {
                int row = rt * 16 + lg * 4 + i;
                wsf[U2_F + (size_t)(n0 + row) * H + pc] = a3[rt][i] + bb;
                wsf[V2_F + (size_t)(n0 + row) * H + pc] = a4[rt][i];
            }
    }
}

// ---------------- edge update: persistent, NPER nodes/block, double-buffered stage ----------------
__global__ __launch_bounds__(256, 3) void edge_kernel(
    const float* __restrict__ hE, const float* __restrict__ b12,
    const float* __restrict__ b13, const float* __restrict__ g3,
    const float* __restrict__ be3, const int* __restrict__ Eidx,
    const bf16* __restrict__ ws, const float* __restrict__ wsf,
    float* __restrict__ outE)
{
    // 40704 B: sAbuf0 @0, sAbuf1 @13056, sH2 @26112, sP1 @39168 (768), sP2 @39936 (768)
    __shared__ __align__(16) char smem[40704];
    bf16 (*sH2)[136] = (bf16(*)[136])(smem + 26112);
    float (*sP1)[4]  = (float(*)[4])(smem + 39168);
    float (*sP2)[4]  = (float(*)[4])(smem + 39936);

    int t = threadIdx.x, w = t >> 6, l = t & 63, l16 = l & 15, lg = l >> 4;
    int col0 = w * 32 + l16, col1 = col0 + 16;
    int pcol = w * 32 + l16 * 2;
    float b12v0 = b12[col0], b12v1 = b12[col1];
    float b13v0 = b13[col0], b13v1 = b13[col1];
    float g3v0 = g3[col0], g3v1 = g3[col1];
    float be3v0 = be3[col0], be3v1 = be3[col1];

    int n0b = blockIdx.x * NPER, b = n0b >> 11;

    // ---- prologue ----
    f32x2 u2p = *(const f32x2*)(wsf + U2_F + (size_t)n0b * H + pcol);
    float v2a[3][4], v2b[3][4];
    #pragma unroll
    for (int rt = 0; rt < 3; ++rt)
        #pragma unroll
        for (int i = 0; i < 4; ++i) {
            int row = rt * 16 + lg * 4 + i;
            int nbr = Eidx[n0b * 48 + row];
            f32x2 vv = *(const f32x2*)(wsf + V2_F + ((size_t)b * NN + nbr) * H + pcol);
            v2a[rt][i] = vv[0]; v2b[rt][i] = vv[1];
        }
    {
        bf16 (*sA0)[136] = (bf16(*)[136])smem;
        #pragma unroll
        for (int i = 0; i < 6; ++i) {
            int idx = t + i * 256, row = idx >> 5, q = idx & 31;
            int c0 = (q >> 3) * 32 + (q & 7) * 2;
            const float* hp = hE + ((size_t)n0b * 48 + row) * H + c0;
            f32x2 a = *(const f32x2*)hp, c = *(const f32x2*)(hp + 16);
            bf16x4 o; o[0] = (bf16)a[0]; o[1] = (bf16)c[0]; o[2] = (bf16)a[1]; o[3] = (bf16)c[1];
            *(bf16x4*)(&sA0[row][q * 4]) = o;
        }
    }
    __syncthreads();

    int cur = 0;
    #pragma unroll 1
    for (int it = 0; it < NPER; ++it) {
        int n = n0b + it;
        bf16 (*sA)[136]  = (bf16(*)[136])(smem + cur * 13056);
        bf16 (*sAn)[136] = (bf16(*)[136])(smem + (cur ^ 1) * 13056);

        // issue next hE loads
        f32x2 nga[6], ngc[6];
        if (it + 1 < NPER) {
            #pragma unroll
            for (int i = 0; i < 6; ++i) {
                int idx = t + i * 256, row = idx >> 5, q = idx & 31;
                int c0 = (q >> 3) * 32 + (q & 7) * 2;
                const float* hp = hE + ((size_t)(n + 1) * 48 + row) * H + c0;
                nga[i] = *(const f32x2*)hp; ngc[i] = *(const f32x2*)(hp + 16);
            }
        }

        // ---- G1 ----
        f32x4 acc[3][2];
        #pragma unroll
        for (int rt = 0; rt < 3; ++rt)
            #pragma unroll
            for (int c2 = 0; c2 < 2; ++c2) acc[rt][c2] = (f32x4){0.f, 0.f, 0.f, 0.f};
        {
            const bf16* B0 = ws + 98304 + (size_t)col0 * 384 + 128 + lg * 8;
            const bf16* B1 = ws + 98304 + (size_t)col1 * 384 + 128 + lg * 8;
            GEMM_PIPE(4, (*(const bf16x8*)(&sA[rt * 16 + l16][u * 32 + lg * 8])), B0, B1, acc)
        }
        // residual capture (bf16 pairs) before overlay
        unsigned rvp[3][4];
        #pragma unroll
        for (int rt = 0; rt < 3; ++rt)
            #pragma unroll
            for (int i = 0; i < 4; ++i)
                rvp[rt][i] = *(const unsigned*)&sA[rt * 16 + lg * 4 + i][pcol];
        __syncthreads();   // all sA reads done

        // epi1 -> sH1 (= sA region)
        #pragma unroll
        for (int rt = 0; rt < 3; ++rt)
            #pragma unroll
            for (int i = 0; i < 4; ++i) {
                int row = rt * 16 + lg * 4 + i;
                bf16 v0 = (bf16)gelu_f(acc[rt][0][i] + u2p[0] + v2a[rt][i]);
                bf16 v1 = (bf16)gelu_f(acc[rt][1][i] + u2p[1] + v2b[rt][i]);
                PACK_STORE(sA, row, pcol, v0, v1)
            }

        // write next stage -> sAn
        if (it + 1 < NPER) {
            #pragma unroll
            for (int i = 0; i < 6; ++i) {
                int idx = t + i * 256, row = idx >> 5, q = idx & 31;
                bf16x4 o; o[0] = (bf16)nga[i][0]; o[1] = (bf16)ngc[i][0];
                o[2] = (bf16)nga[i][1]; o[3] = (bf16)ngc[i][1];
                *(bf16x4*)(&sAn[row][q * 4]) = o;
            }
        }

        // next scalars
        f32x2 u2pn; float v2an[3][4], v2bn[3][4];
        if (it + 1 < NPER) {
            u2pn = *(const f32x2*)(wsf + U2_F + (size_t)(n + 1) * H + pcol);
            #pragma unroll
            for (int rt = 0; rt < 3; ++rt)
                #pragma unroll
                for (int i = 0; i < 4; ++i) {
                    int row = rt * 16 + lg * 4 + i;
                    int nbr = Eidx[(n + 1) * 48 + row];
                    f32x2 vv = *(const f32x2*)(wsf + V2_F + ((size_t)b * NN + nbr) * H + pcol);
                    v2an[rt][i] = vv[0]; v2bn[rt][i] = vv[1];
                }
        }
        __syncthreads();   // sH1 + sAn visible

        // ---- G2 ----
        f32x4 a2[3][2];
        #pragma unroll
        for (int rt = 0; rt < 3; ++rt)
            #pragma unroll
            for (int c2 = 0; c2 < 2; ++c2) a2[rt][c2] = (f32x4){0.f, 0.f, 0.f, 0.f};
        {
            const bf16* B0 = ws + 147456 + (size_t)col0 * 128 + lg * 8;
            const bf16* B1 = ws + 147456 + (size_t)col1 * 128 + lg * 8;
            GEMM_PIPE(4, (*(const bf16x8*)(&sA[rt * 16 + l16][u * 32 + lg * 8])), B0, B1, a2)
        }
        // epi2 -> sH2
        #pragma unroll
        for (int rt = 0; rt < 3; ++rt)
            #pragma unroll
            for (int i = 0; i < 4; ++i) {
                int row = rt * 16 + lg * 4 + i;
                bf16 v0 = (bf16)gelu_f(a2[rt][0][i] + b12v0);
                bf16 v1 = (bf16)gelu_f(a2[rt][1][i] + b12v1);
                PACK_STORE(sH2, row, pcol, v0, v1)
            }
        __syncthreads();

        // ---- G3 ----
        f32x4 a3[3][2];
        #pragma unroll
        for (int rt = 0; rt < 3; ++rt)
            #pragma unroll
            for (int c2 = 0; c2 < 2; ++c2) a3[rt][c2] = (f32x4){0.f, 0.f, 0.f, 0.f};
        {
            const bf16* B0 = ws + 163840 + (size_t)col0 * 128 + lg * 8;
            const bf16* B1 = ws + 163840 + (size_t)col1 * 128 + lg * 8;
            GEMM_PIPE(4, (*(const bf16x8*)(&sH2[rt * 16 + l16][u * 32 + lg * 8])), B0, B1, a3)
        }

        // epi3: v = m3 + b13 + hE(residual); per-row moments
        float s1r[3][4], s2r[3][4];
        #pragma unroll
        for (int rt = 0; rt < 3; ++rt)
            #pragma unroll
            for (int i = 0; i < 4; ++i) {
                union { unsigned u; bf16 h[2]; } rp; rp.u = rvp[rt][i];
                float v0 = a3[rt][0][i] + b13v0 + (float)rp.h[0];
                float v1 = a3[rt][1][i] + b13v1 + (float)rp.h[1];
                a3[rt][0][i] = v0; a3[rt][1][i] = v1;
                s1r[rt][i] = v0 + v1; s2r[rt][i] = v0 * v0 + v1 * v1;
            }
        #pragma unroll
        for (int mseg = 1; mseg < 16; mseg <<= 1)
            #pragma unroll
            for (int rt = 0; rt < 3; ++rt)
                #pragma unroll
                for (int i = 0; i < 4; ++i) {
                    s1r[rt][i] += __shfl_xor(s1r[rt][i], mseg);
                    s2r[rt][i] += __shfl_xor(s2r[rt][i], mseg);
                }
        if (l16 == 0) {
            #pragma unroll
            for (int rt = 0; rt < 3; ++rt)
                #pragma unroll
                for (int i = 0; i < 4; ++i) {
                    int row = rt * 16 + lg * 4 + i;
                    sP1[row][w] = s1r[rt][i];
                    sP2[row][w] = s2r[rt][i];
                }
        }
        __syncthreads();

        // finalize LN3 + store
        #pragma unroll
        for (int rt = 0; rt < 3; ++rt)
            #pragma unroll
            for (int i = 0; i < 4; ++i) {
                int row = rt * 16 + lg * 4 + i;
                f32x4 p1 = *(const f32x4*)sP1[row];
                f32x4 p2 = *(const f32x4*)sP2[row];
                float s1 = p1[0] + p1[1] + p1[2] + p1[3];
                float s2 = p2[0] + p2[1] + p2[2] + p2[3];
                float mn = s1 * (1.f / 128.f);
                float rs = rsqrtf(s2 * (1.f / 128.f) - mn * mn + EPSF);
                size_t rb = ((size_t)n * 48 + row) * H;
                outE[rb + col0] = (a3[rt][0][i] - mn) * rs * g3v0 + be3v0;
                outE[rb + col1] = (a3[rt][1][i] - mn) * rs * g3v1 + be3v1;
            }

        // rotate
        if (it + 1 < NPER) {
            u2p = u2pn;
            #pragma unroll
            for (int rt = 0; rt < 3; ++rt)
                #pragma unroll
                for (int i = 0; i < 4; ++i) { v2a[rt][i] = v2an[rt][i]; v2b[rt][i] = v2bn[rt][i]; }
        }
        cur ^= 1;
        __syncthreads();   // conservative loop-boundary barrier
    }
}

extern "C" void kernel_launch(void* const* d_in, const int* in_sizes, int n_in,
                              void* d_out, int out_size, void* d_ws, size_t ws_size,
                              hipStream_t stream)
{
    const float* hV    = (const float*)d_in[0];
    const float* hVa   = (const float*)d_in[1];
    const float* hE    = (const float*)d_in[2];
    const float* W1    = (const float*)d_in[3];
    const float* b1    = (const float*)d_in[4];
    const float* W2    = (const float*)d_in[5];
    const float* b2    = (const float*)d_in[6];
    const float* W3    = (const float*)d_in[7];
    const float* b3    = (const float*)d_in[8];
    const float* W11   = (const float*)d_in[9];
    const float* b11   = (const float*)d_in[10];
    const float* W12   = (const float*)d_in[11];
    const float* b12   = (const float*)d_in[12];
    const float* W13   = (const float*)d_in[13];
    const float* b13   = (const float*)d_in[14];
    const float* Win   = (const float*)d_in[15];
    const float* b_in  = (const float*)d_in[16];
    const float* Wout  = (const float*)d_in[17];
    const float* b_out = (const float*)d_in[18];
    const float* g1    = (const float*)d_in[19];
    const float* be1   = (const float*)d_in[20];
    const float* g2    = (const float*)d_in[21];
    const float* be2   = (const float*)d_in[22];
    const float* g3    = (const float*)d_in[23];
    const float* be3   = (const float*)d_in[24];
    const float* maskV = (const float*)d_in[25];
    const float* maskA = (const float*)d_in[26];
    const int*   Eidx  = (const int*)  d_in[27];

    bf16*  ws   = (bf16*)d_ws;
    float* wsf  = (float*)d_ws;
    float* outV = (float*)d_out;
    float* outE = outV + (size_t)BB * NN * H;

    prep_weights<<<1216, 256, 0, stream>>>(W1, W2, W3, W11, W12, W13, Win, Wout, ws);
    u1_kernel<<<32, 512, 0, stream>>>(hV, hVa, b1, ws, wsf);
    node_msg_kernel<<<BB * NN / NPER, 256, 0, stream>>>(hV, hE, b2, b3, g1, be1, maskA, Eidx, ws, wsf);
    ffn_kernel<<<BB * NN / 32, 512, 0, stream>>>(b_in, b_out, b11, g2, be2, maskV, ws, wsf, outV);
    edge_kernel<<<BB * NN / NPER, 256, 0, stream>>>(hE, b12, b13, g3, be3, Eidx, ws, wsf, outE);
}

// Round 19
// 174.351 us; speedup vs baseline: 2.6475x; 2.6475x over previous
//
#include <hip/hip_runtime.h>
#include <hip/hip_bf16.h>

#define H 128
#define NN 2048
#define BB 2
#define EPSF 1e-5f

typedef __bf16 bf16;
typedef bf16 bf16x8 __attribute__((ext_vector_type(8)));
typedef bf16 bf16x4 __attribute__((ext_vector_type(4)));
typedef float f32x4 __attribute__((ext_vector_type(4)));

// ---- ws layout ----
// bf16 elems [0, 311296): weights
//   Wm1T full [128][512] @ 0      (k segs: self | hE-fold | hV_nb | hVa_nb)
//   W2T   @ 65536, W3T @ 81920   (k-dim PERMUTED by phi)
//   W11T full [128][384] @ 98304  (k segs: self | hE | hV2_nb)
//   W12T  @ 147456, W13T @ 163840 (k-dim PERMUTED by phi)
//   WinT [512][128] @ 180224, WoutT [128][512] @ 245760
// phi(c) = (c&~31) + (c&15)*2 + ((c>>4)&1)
// f32 elems (on (float*)ws):
#define U1_F     155648
#define U2_F     679936
#define HVMID_F  1204224
#define V2_F     1990656   // hV2 @ W11c   [4096][128] f32
#define V1_F     2252800   // hV@W1c+hVa@W1d [4096][128] f32
// bf16 elems:
#define HVMID_B  3457024

__device__ __forceinline__ float gelu_f(float x) {
    float u = x * x;
    float p = __builtin_fmaf(u, 0.044715f, 1.0f);
    float w = x * p;
    float e = __builtin_amdgcn_exp2f(w * -2.3022083f);
    return x * __builtin_amdgcn_rcpf(1.0f + e);
}

#define MFMA16(a, b, c) __builtin_amdgcn_mfma_f32_16x16x32_bf16((a), (b), (c), 0, 0, 0)

// Deep-pipelined GEMM phase: U units, 3-deep B prefetch, 1-deep A prefetch.
// Slot uu%3 is consumed first, then refilled with unit uu+3.
#define GEMM_PIPE(U, A_EXPR, B0p, B1p, ACC)                                       \
    {                                                                             \
        bf16x8 bq0[3], bq1[3];                                                    \
        _Pragma("unroll")                                                         \
        for (int j = 0; j < 3 && j < (U); ++j) {                                  \
            bq0[j] = *(const bf16x8*)((B0p) + j * 32);                            \
            bq1[j] = *(const bf16x8*)((B1p) + j * 32);                            \
        }                                                                         \
        bf16x8 afc[3], afn[3];                                                    \
        _Pragma("unroll")                                                         \
        for (int rt = 0; rt < 3; ++rt) { const int u = 0; afc[rt] = (A_EXPR); }   \
        _Pragma("unroll")                                                         \
        for (int uu = 0; uu < (U); ++uu) {                                        \
            if (uu + 1 < (U)) {                                                   \
                _Pragma("unroll")                                                 \
                for (int rt = 0; rt < 3; ++rt) { const int u = uu + 1; afn[rt] = (A_EXPR); } \
            }                                                                     \
            __builtin_amdgcn_s_setprio(1);                                        \
            _Pragma("unroll")                                                     \
            for (int rt = 0; rt < 3; ++rt) {                                      \
                ACC[rt][0] = MFMA16(afc[rt], bq0[uu % 3], ACC[rt][0]);            \
                ACC[rt][1] = MFMA16(afc[rt], bq1[uu % 3], ACC[rt][1]);            \
            }                                                                     \
            __builtin_amdgcn_s_setprio(0);                                        \
            if (uu + 3 < (U)) {                                                   \
                bq0[uu % 3] = *(const bf16x8*)((B0p) + (uu + 3) * 32);            \
                bq1[uu % 3] = *(const bf16x8*)((B1p) + (uu + 3) * 32);            \
            }                                                                     \
            _Pragma("unroll")                                                     \
            for (int rt = 0; rt < 3; ++rt) afc[rt] = afn[rt];                     \
        }                                                                         \
    }

// packed pair write: two logical cols (c, c+16) -> physical (pcol, pcol+1), one b32 store
#define PACK_STORE(DST, ROW, PCOL, V0, V1)                                        \
    {                                                                             \
        union { bf16 h[2]; unsigned u; } pk_;                                     \
        pk_.h[0] = (V0); pk_.h[1] = (V1);                                         \
        *(unsigned*)&DST[ROW][PCOL] = pk_.u;                                      \
    }

// ---------------- weight prep ----------------
__global__ void prep_weights(const float* __restrict__ W1, const float* __restrict__ W2,
                             const float* __restrict__ W3, const float* __restrict__ W11,
                             const float* __restrict__ W12, const float* __restrict__ W13,
                             const float* __restrict__ Win, const float* __restrict__ Wout,
                             bf16* __restrict__ ws)
{
    int i = blockIdx.x * 256 + threadIdx.x;
    float v;
    if (i < 65536) {
        int c = i >> 9, k = i & 511, s = k >> 7, k0 = k & 127;
        if (s == 0)      v = W1[k0 * H + c];
        else if (s == 1) v = W1[(128 + k0) * H + c] + W1[(384 + k0) * H + c];
        else if (s == 2) v = W1[(256 + k0) * H + c];
        else             v = W1[(512 + k0) * H + c];
    } else if (i < 81920)  { int j = i - 65536;  int c = j >> 7, p = j & 127;
                             int k = (p & ~31) + ((p & 1) << 4) + ((p & 31) >> 1);
                             v = W2[k * H + c]; }
    else if (i < 98304)    { int j = i - 81920;  int c = j >> 7, p = j & 127;
                             int k = (p & ~31) + ((p & 1) << 4) + ((p & 31) >> 1);
                             v = W3[k * H + c]; }
    else if (i < 147456)   { int j = i - 98304;  int c = j / 384, k = j - c * 384; v = W11[k * H + c]; }
    else if (i < 163840)   { int j = i - 147456; int c = j >> 7, p = j & 127;
                             int k = (p & ~31) + ((p & 1) << 4) + ((p & 31) >> 1);
                             v = W12[k * H + c]; }
    else if (i < 180224)   { int j = i - 163840; int c = j >> 7, p = j & 127;
                             int k = (p & ~31) + ((p & 1) << 4) + ((p & 31) >> 1);
                             v = W13[k * H + c]; }
    else if (i < 245760)   { int j = i - 180224; int jj = j >> 7, k = j & 127; v = Win[k * 512 + jj]; }
    else                   { int j = i - 245760; int c = j >> 9, k = j & 511; v = Wout[k * H + c]; }
    ws[i] = (bf16)v;
}

// ---------------- u1: U1 = hV@W1a + b1 ; V1 = hV@W1c + hVa@W1d ----------------
__global__ __launch_bounds__(512) void u1_kernel(
    const float* __restrict__ hV, const float* __restrict__ hVa,
    const float* __restrict__ b1, const bf16* __restrict__ ws, float* __restrict__ wsf)
{
    int n0 = blockIdx.x * 128;
    int t = threadIdx.x, w = t >> 6, l = t & 63, l16 = l & 15, lg = l >> 4;
    int wm = w >> 2, wn = w & 3;
    __shared__ __align__(16) bf16 sA[128][136];   // hV
    __shared__ __align__(16) bf16 sB[128][136];   // hVa

    #pragma unroll
    for (int i = 0; i < 8; ++i) {
        int idx = t + i * 512;
        int row = idx >> 5, c4 = (idx & 31) << 2;
        f32x4 v = *(const f32x4*)(hV + (size_t)(n0 + row) * H + c4);
        bf16x4 o; o[0] = (bf16)v[0]; o[1] = (bf16)v[1]; o[2] = (bf16)v[2]; o[3] = (bf16)v[3];
        *(bf16x4*)(&sA[row][c4]) = o;
        f32x4 va = *(const f32x4*)(hVa + (size_t)(n0 + row) * H + c4);
        bf16x4 oa; oa[0] = (bf16)va[0]; oa[1] = (bf16)va[1]; oa[2] = (bf16)va[2]; oa[3] = (bf16)va[3];
        *(bf16x4*)(&sB[row][c4]) = oa;
    }
    __syncthreads();

    f32x4 accU[4][2], accV[4][2];
    #pragma unroll
    for (int rt = 0; rt < 4; ++rt)
        #pragma unroll
        for (int c2 = 0; c2 < 2; ++c2) {
            accU[rt][c2] = (f32x4){0.f, 0.f, 0.f, 0.f};
            accV[rt][c2] = (f32x4){0.f, 0.f, 0.f, 0.f};
        }
    // U1 (seg 0) and V1 part 1 (hV x seg 256)
    #pragma unroll
    for (int kk = 0; kk < 4; ++kk) {
        bf16x8 af[4];
        #pragma unroll
        for (int rt = 0; rt < 4; ++rt)
            af[rt] = *(const bf16x8*)(&sA[wm * 64 + rt * 16 + l16][kk * 32 + lg * 8]);
        #pragma unroll
        for (int c2 = 0; c2 < 2; ++c2) {
            int c = wn * 32 + c2 * 16 + l16;
            bf16x8 bU = *(const bf16x8*)(&ws[(size_t)c * 512 + kk * 32 + lg * 8]);
            bf16x8 bV = *(const bf16x8*)(&ws[(size_t)c * 512 + 256 + kk * 32 + lg * 8]);
            #pragma unroll
            for (int rt = 0; rt < 4; ++rt) {
                accU[rt][c2] = MFMA16(af[rt], bU, accU[rt][c2]);
                accV[rt][c2] = MFMA16(af[rt], bV, accV[rt][c2]);
            }
        }
    }
    // V1 part 2 (hVa x seg 384)
    #pragma unroll
    for (int kk = 0; kk < 4; ++kk) {
        bf16x8 af[4];
        #pragma unroll
        for (int rt = 0; rt < 4; ++rt)
            af[rt] = *(const bf16x8*)(&sB[wm * 64 + rt * 16 + l16][kk * 32 + lg * 8]);
        #pragma unroll
        for (int c2 = 0; c2 < 2; ++c2) {
            int c = wn * 32 + c2 * 16 + l16;
            bf16x8 bV = *(const bf16x8*)(&ws[(size_t)c * 512 + 384 + kk * 32 + lg * 8]);
            #pragma unroll
            for (int rt = 0; rt < 4; ++rt)
                accV[rt][c2] = MFMA16(af[rt], bV, accV[rt][c2]);
        }
    }
    #pragma unroll
    for (int c2 = 0; c2 < 2; ++c2) {
        int col = wn * 32 + c2 * 16 + l16;
        float bb = b1[col];
        #pragma unroll
        for (int rt = 0; rt < 4; ++rt)
            #pragma unroll
            for (int i = 0; i < 4; ++i) {
                int row = wm * 64 + rt * 16 + lg * 4 + i;
                wsf[U1_F + (size_t)(n0 + row) * H + col] = accU[rt][c2][i] + bb;
                wsf[V1_F + (size_t)(n0 + row) * H + col] = accV[rt][c2][i];
            }
    }
}

// ---------------- node message: 1 node/block, M=48, K=128 G1 + V1 table ----------------
__global__ __launch_bounds__(256, 4) void node_msg_kernel(
    const float* __restrict__ hV, const float* __restrict__ hE,
    const float* __restrict__ b2, const float* __restrict__ b3,
    const float* __restrict__ g1, const float* __restrict__ be1,
    const float* __restrict__ maskA, const int* __restrict__ Eidx,
    bf16* __restrict__ ws, float* __restrict__ wsf)
{
    // 27136 B: sA [48][136]=13056 (sH1 overlays); sH2 @13056; sDH @26112
    __shared__ __align__(16) char smem[27136];
    bf16 (*sA)[136]  = (bf16(*)[136])smem;
    bf16 (*sH1)[136] = (bf16(*)[136])smem;
    bf16 (*sH2)[136] = (bf16(*)[136])(smem + 13056);
    float* sDH = (float*)(smem + 26112);

    int n = blockIdx.x, b = n >> 11;
    int t = threadIdx.x, w = t >> 6, l = t & 63, l16 = l & 15, lg = l >> 4;

    int col0 = w * 32 + l16, col1 = col0 + 16;
    int pcol = w * 32 + l16 * 2;
    float u1v0 = wsf[U1_F + (size_t)n * H + col0];
    float u1v1 = wsf[U1_F + (size_t)n * H + col1];
    float b2v0 = b2[col0], b2v1 = b2[col1];
    float b3v0 = b3[col0], b3v1 = b3[col1];

    // ---- V1 prefetch: per-thread 12 rows x 2 cols from L2-resident table ----
    float v1v0[3][4], v1v1[3][4];
    #pragma unroll
    for (int rt = 0; rt < 3; ++rt)
        #pragma unroll
        for (int i = 0; i < 4; ++i) {
            int row = rt * 16 + lg * 4 + i;
            int nbr = Eidx[n * 48 + row];
            const float* vp = wsf + V1_F + ((size_t)b * NN + nbr) * H;
            v1v0[rt][i] = vp[col0];
            v1v1[rt][i] = vp[col1];
        }

    // ---- stage hE (f32->bf16) ----
    #pragma unroll
    for (int i = 0; i < 6; ++i) {
        int idx = t + i * 256;
        int row = idx >> 5, c4 = (idx & 31) << 2;
        f32x4 v = *(const f32x4*)(hE + ((size_t)n * 48 + row) * H + c4);
        bf16x4 o; o[0] = (bf16)v[0]; o[1] = (bf16)v[1]; o[2] = (bf16)v[2]; o[3] = (bf16)v[3];
        *(bf16x4*)(&sA[row][c4]) = o;
    }
    __syncthreads();

    // ---- G1: 48x128 @ 128x128 (hE-fold seg @128) ----
    f32x4 acc[3][2];
    #pragma unroll
    for (int rt = 0; rt < 3; ++rt)
        #pragma unroll
        for (int c2 = 0; c2 < 2; ++c2) acc[rt][c2] = (f32x4){0.f, 0.f, 0.f, 0.f};
    {
        const bf16* B0 = ws + (size_t)col0 * 512 + 128 + lg * 8;
        const bf16* B1 = ws + (size_t)col1 * 512 + 128 + lg * 8;
        GEMM_PIPE(4, (*(const bf16x8*)(&sA[rt * 16 + l16][u * 32 + lg * 8])), B0, B1, acc)
    }
    __syncthreads();   // all sA reads done -> sH1 overlay safe

    // epi1: gelu(acc + U1 + V1[nbr]) -> sH1 (packed phi layout)
    #pragma unroll
    for (int rt = 0; rt < 3; ++rt)
        #pragma unroll
        for (int i = 0; i < 4; ++i) {
            int row = rt * 16 + lg * 4 + i;
            bf16 v0 = (bf16)gelu_f(acc[rt][0][i] + u1v0 + v1v0[rt][i]);
            bf16 v1 = (bf16)gelu_f(acc[rt][1][i] + u1v1 + v1v1[rt][i]);
            PACK_STORE(sH1, row, pcol, v0, v1)
        }
    __syncthreads();

    // ---- G2: A=sH1 (phi-physical), B=W2T (k-permuted) ----
    f32x4 a2[3][2];
    #pragma unroll
    for (int rt = 0; rt < 3; ++rt)
        #pragma unroll
        for (int c2 = 0; c2 < 2; ++c2) a2[rt][c2] = (f32x4){0.f, 0.f, 0.f, 0.f};
    {
        const bf16* B0 = ws + 65536 + (size_t)col0 * 128 + lg * 8;
        const bf16* B1 = ws + 65536 + (size_t)col1 * 128 + lg * 8;
        GEMM_PIPE(4, (*(const bf16x8*)(&sH1[rt * 16 + l16][u * 32 + lg * 8])), B0, B1, a2)
    }
    // epi2 -> sH2 (packed; disjoint region)
    #pragma unroll
    for (int rt = 0; rt < 3; ++rt)
        #pragma unroll
        for (int i = 0; i < 4; ++i) {
            int row = rt * 16 + lg * 4 + i;
            bf16 v0 = (bf16)gelu_f(a2[rt][0][i] + b2v0);
            bf16 v1 = (bf16)gelu_f(a2[rt][1][i] + b2v1);
            PACK_STORE(sH2, row, pcol, v0, v1)
        }
    __syncthreads();

    float mk[3][4];
    #pragma unroll
    for (int rt = 0; rt < 3; ++rt)
        #pragma unroll
        for (int i = 0; i < 4; ++i)
            mk[rt][i] = maskA[n * 48 + rt * 16 + lg * 4 + i];

    // ---- G3: A=sH2 (phi-physical), B=W3T (k-permuted) ----
    f32x4 a3[3][2];
    #pragma unroll
    for (int rt = 0; rt < 3; ++rt)
        #pragma unroll
        for (int c2 = 0; c2 < 2; ++c2) a3[rt][c2] = (f32x4){0.f, 0.f, 0.f, 0.f};
    {
        const bf16* B0 = ws + 81920 + (size_t)col0 * 128 + lg * 8;
        const bf16* B1 = ws + 81920 + (size_t)col1 * 128 + lg * 8;
        GEMM_PIPE(4, (*(const bf16x8*)(&sH2[rt * 16 + l16][u * 32 + lg * 8])), B0, B1, a3)
    }
    float r0s = 0.f, r1s = 0.f;
    #pragma unroll
    for (int rt = 0; rt < 3; ++rt)
        #pragma unroll
        for (int i = 0; i < 4; ++i) {
            r0s += (a3[rt][0][i] + b3v0) * mk[rt][i];
            r1s += (a3[rt][1][i] + b3v1) * mk[rt][i];
        }
    r0s += __shfl_xor(r0s, 16); r0s += __shfl_xor(r0s, 32);
    r1s += __shfl_xor(r1s, 16); r1s += __shfl_xor(r1s, 32);
    if (l < 16) { sDH[w * 32 + l] = r0s; sDH[w * 32 + 16 + l] = r1s; }
    __syncthreads();

    if (w == 0) {
        float x0 = hV[(size_t)n * H + l] + sDH[l] * (1.0f / 30.0f);
        float x1 = hV[(size_t)n * H + l + 64] + sDH[l + 64] * (1.0f / 30.0f);
        float s1 = x0 + x1, s2 = x0 * x0 + x1 * x1;
        #pragma unroll
        for (int off = 32; off; off >>= 1) { s1 += __shfl_xor(s1, off); s2 += __shfl_xor(s2, off); }
        float m = s1 * (1.f / 128.f);
        float rs = rsqrtf(s2 * (1.f / 128.f) - m * m + EPSF);
        float y0 = (x0 - m) * rs * g1[l] + be1[l];
        float y1 = (x1 - m) * rs * g1[l + 64] + be1[l + 64];
        wsf[HVMID_F + (size_t)n * H + l] = y0;
        wsf[HVMID_F + (size_t)n * H + l + 64] = y1;
        ws[HVMID_B + (size_t)n * H + l] = (bf16)y0;
        ws[HVMID_B + (size_t)n * H + l + 64] = (bf16)y1;
    }
}

// ---------------- FFN batched: 32 nodes/block, + LN2 + maskV + U2 + V2 ----------------
__global__ __launch_bounds__(512) void ffn_kernel(
    const float* __restrict__ b_in, const float* __restrict__ b_out,
    const float* __restrict__ b11, const float* __restrict__ g2,
    const float* __restrict__ be2, const float* __restrict__ maskV,
    bf16* __restrict__ ws, float* __restrict__ wsf, float* __restrict__ outV)
{
    int n0 = blockIdx.x * 32;
    int t = threadIdx.x, w = t >> 6, l = t & 63, l16 = l & 15, lg = l >> 4;

    __shared__ __align__(16) char smem[8704 + 33280];
    bf16 (*sA)[136]  = (bf16(*)[136])(smem);
    bf16 (*sFF)[520] = (bf16(*)[520])(smem + 8704);
    float (*sX)[132] = (float(*)[132])(smem + 8704);

    {
        int row = t >> 4, c8 = (t & 15) << 3;
        *(bf16x8*)(&sA[row][c8]) = *(const bf16x8*)(ws + HVMID_B + (size_t)(n0 + row) * H + c8);
    }
    __syncthreads();

    f32x4 a1[2][4];
    #pragma unroll
    for (int rt = 0; rt < 2; ++rt)
        #pragma unroll
        for (int ct = 0; ct < 4; ++ct) a1[rt][ct] = (f32x4){0.f, 0.f, 0.f, 0.f};
    #pragma unroll
    for (int kk = 0; kk < 4; ++kk) {
        bf16x8 af[2];
        #pragma unroll
        for (int rt = 0; rt < 2; ++rt)
            af[rt] = *(const bf16x8*)(&sA[rt * 16 + l16][kk * 32 + lg * 8]);
        #pragma unroll
        for (int ct = 0; ct < 4; ++ct) {
            int c = w * 64 + ct * 16 + l16;
            bf16x8 bfr = *(const bf16x8*)(&ws[180224 + (size_t)c * 128 + kk * 32 + lg * 8]);
            #pragma unroll
            for (int rt = 0; rt < 2; ++rt)
                a1[rt][ct] = MFMA16(af[rt], bfr, a1[rt][ct]);
        }
    }
    #pragma unroll
    for (int ct = 0; ct < 4; ++ct) {
        int c = w * 64 + ct * 16 + l16;
        float bb = b_in[c];
        #pragma unroll
        for (int rt = 0; rt < 2; ++rt)
            #pragma unroll
            for (int i = 0; i < 4; ++i) {
                int row = rt * 16 + lg * 4 + i;
                sFF[row][c] = (bf16)gelu_f(a1[rt][ct][i] + bb);
            }
    }
    __syncthreads();

    f32x4 a2[2];
    a2[0] = (f32x4){0.f, 0.f, 0.f, 0.f}; a2[1] = (f32x4){0.f, 0.f, 0.f, 0.f};
    int cc = w * 16 + l16;
    #pragma unroll
    for (int kk = 0; kk < 16; ++kk) {
        bf16x8 af[2];
        #pragma unroll
        for (int rt = 0; rt < 2; ++rt)
            af[rt] = *(const bf16x8*)(&sFF[rt * 16 + l16][kk * 32 + lg * 8]);
        bf16x8 bfr = *(const bf16x8*)(&ws[245760 + (size_t)cc * 512 + kk * 32 + lg * 8]);
        #pragma unroll
        for (int rt = 0; rt < 2; ++rt)
            a2[rt] = MFMA16(af[rt], bfr, a2[rt]);
    }
    __syncthreads();
    {
        float bb = b_out[cc];
        #pragma unroll
        for (int rt = 0; rt < 2; ++rt)
            #pragma unroll
            for (int i = 0; i < 4; ++i) {
                int row = rt * 16 + lg * 4 + i;
                sX[row][cc] = a2[rt][i] + bb + wsf[HVMID_F + (size_t)(n0 + row) * H + cc];
            }
    }
    __syncthreads();

    if (t < 128) {
        int row = t >> 2, q = t & 3;
        float xr[32], s1 = 0.f, s2 = 0.f;
        #pragma unroll
        for (int j = 0; j < 32; ++j) {
            float x = sX[row][q * 32 + j];
            xr[j] = x; s1 += x; s2 += x * x;
        }
        s1 += __shfl_xor(s1, 1); s1 += __shfl_xor(s1, 2);
        s2 += __shfl_xor(s2, 1); s2 += __shfl_xor(s2, 2);
        float m = s1 * (1.f / 128.f);
        float vv = s2 * (1.f / 128.f) - m * m;
        float rs = rsqrtf(vv + EPSF);
        float mv = maskV[n0 + row];
        #pragma unroll
        for (int j = 0; j < 32; ++j) {
            int c = q * 32 + j;
            float y = ((xr[j] - m) * rs * g2[c] + be2[c]) * mv;
            outV[(size_t)(n0 + row) * H + c] = y;
            sA[row][c] = (bf16)y;
        }
    }
    __syncthreads();

    // U2 = hV2 @ W11a + b11 ; V2 = hV2 @ W11c
    f32x4 a3[2], a4[2];
    a3[0] = (f32x4){0.f, 0.f, 0.f, 0.f}; a3[1] = (f32x4){0.f, 0.f, 0.f, 0.f};
    a4[0] = (f32x4){0.f, 0.f, 0.f, 0.f}; a4[1] = (f32x4){0.f, 0.f, 0.f, 0.f};
    #pragma unroll
    for (int kk = 0; kk < 4; ++kk) {
        bf16x8 af[2];
        #pragma unroll
        for (int rt = 0; rt < 2; ++rt)
            af[rt] = *(const bf16x8*)(&sA[rt * 16 + l16][kk * 32 + lg * 8]);
        bf16x8 bU = *(const bf16x8*)(&ws[98304 + (size_t)cc * 384 + kk * 32 + lg * 8]);
        bf16x8 bV = *(const bf16x8*)(&ws[98304 + (size_t)cc * 384 + 256 + kk * 32 + lg * 8]);
        #pragma unroll
        for (int rt = 0; rt < 2; ++rt) {
            a3[rt] = MFMA16(af[rt], bU, a3[rt]);
            a4[rt] = MFMA16(af[rt], bV, a4[rt]);
        }
    }
    {
        float bb = b11[cc];
        #pragma unroll
        for (int rt = 0; rt < 2; ++rt)
            #pragma unroll
            for (int i = 0; i < 4; ++i) {
                int row = rt * 16 + lg * 4 + i;
                wsf[U2_F + (size_t)(n0 + row) * H + cc] = a3[rt][i] + bb;
                wsf[V2_F + (size_t)(n0 + row) * H + cc] = a4[rt][i];
            }
    }
}

// ---------------- edge update: 1 node/block, M=48, K=128 G1 + V2 table ----------------
__global__ __launch_bounds__(256, 4) void edge_kernel(
    const float* __restrict__ hE, const float* __restrict__ b12,
    const float* __restrict__ b13, const float* __restrict__ g3,
    const float* __restrict__ be3, const int* __restrict__ Eidx,
    const bf16* __restrict__ ws, const float* __restrict__ wsf,
    float* __restrict__ outE)
{
    // 26112 B: sA [48][136]=13056 (sH1 overlays); sH2 @13056;
    // sP1 @0, sP2 @1024 overlay dead sH1 region post-G2.
    __shared__ __align__(16) char smem[26112];
    bf16 (*sA)[136]  = (bf16(*)[136])smem;
    bf16 (*sH1)[136] = (bf16(*)[136])smem;
    bf16 (*sH2)[136] = (bf16(*)[136])(smem + 13056);
    float (*sP1)[4]  = (float(*)[4])smem;
    float (*sP2)[4]  = (float(*)[4])(smem + 1024);

    int n = blockIdx.x, b = n >> 11;
    int t = threadIdx.x, w = t >> 6, l = t & 63, l16 = l & 15, lg = l >> 4;

    int col0 = w * 32 + l16, col1 = col0 + 16;
    int pcol = w * 32 + l16 * 2;
    float u2v0 = wsf[U2_F + (size_t)n * H + col0];
    float u2v1 = wsf[U2_F + (size_t)n * H + col1];
    float b12v0 = b12[col0], b12v1 = b12[col1];
    float b13v0 = b13[col0], b13v1 = b13[col1];
    float g3v0 = g3[col0], g3v1 = g3[col1];
    float be3v0 = be3[col0], be3v1 = be3[col1];

    // ---- V2 prefetch ----
    float v2v0[3][4], v2v1[3][4];
    #pragma unroll
    for (int rt = 0; rt < 3; ++rt)
        #pragma unroll
        for (int i = 0; i < 4; ++i) {
            int row = rt * 16 + lg * 4 + i;
            int nbr = Eidx[n * 48 + row];
            const float* vp = wsf + V2_F + ((size_t)b * NN + nbr) * H;
            v2v0[rt][i] = vp[col0];
            v2v1[rt][i] = vp[col1];
        }

    // ---- stage hE (f32->bf16) ----
    #pragma unroll
    for (int i = 0; i < 6; ++i) {
        int idx = t + i * 256;
        int row = idx >> 5, c4 = (idx & 31) << 2;
        f32x4 v = *(const f32x4*)(hE + ((size_t)n * 48 + row) * H + c4);
        bf16x4 o; o[0] = (bf16)v[0]; o[1] = (bf16)v[1]; o[2] = (bf16)v[2]; o[3] = (bf16)v[3];
        *(bf16x4*)(&sA[row][c4]) = o;
    }
    __syncthreads();

    // ---- G1: 48x128 @ 128x128 (hE seg @128 of W11T) ----
    f32x4 acc[3][2];
    #pragma unroll
    for (int rt = 0; rt < 3; ++rt)
        #pragma unroll
        for (int c2 = 0; c2 < 2; ++c2) acc[rt][c2] = (f32x4){0.f, 0.f, 0.f, 0.f};
    {
        const bf16* B0 = ws + 98304 + (size_t)col0 * 384 + 128 + lg * 8;
        const bf16* B1 = ws + 98304 + (size_t)col1 * 384 + 128 + lg * 8;
        GEMM_PIPE(4, (*(const bf16x8*)(&sA[rt * 16 + l16][u * 32 + lg * 8])), B0, B1, acc)
    }

    // residual capture from staged bf16 hE (before overlay barrier)
    float rv[3][2][4];
    #pragma unroll
    for (int rt = 0; rt < 3; ++rt)
        #pragma unroll
        for (int c2 = 0; c2 < 2; ++c2)
            #pragma unroll
            for (int i = 0; i < 4; ++i)
                rv[rt][c2][i] = (float)sA[rt * 16 + lg * 4 + i][c2 ? col1 : col0];
    __syncthreads();   // all sA reads done -> sH1 overlay safe

    // epi1: gelu(acc + U2 + V2[nbr]) -> sH1 (packed)
    #pragma unroll
    for (int rt = 0; rt < 3; ++rt)
        #pragma unroll
        for (int i = 0; i < 4; ++i) {
            int row = rt * 16 + lg * 4 + i;
            bf16 v0 = (bf16)gelu_f(acc[rt][0][i] + u2v0 + v2v0[rt][i]);
            bf16 v1 = (bf16)gelu_f(acc[rt][1][i] + u2v1 + v2v1[rt][i]);
            PACK_STORE(sH1, row, pcol, v0, v1)
        }
    __syncthreads();

    // ---- G2: A=sH1 (phi), B=W12T (k-permuted) ----
    f32x4 a2[3][2];
    #pragma unroll
    for (int rt = 0; rt < 3; ++rt)
        #pragma unroll
        for (int c2 = 0; c2 < 2; ++c2) a2[rt][c2] = (f32x4){0.f, 0.f, 0.f, 0.f};
    {
        const bf16* B0 = ws + 147456 + (size_t)col0 * 128 + lg * 8;
        const bf16* B1 = ws + 147456 + (size_t)col1 * 128 + lg * 8;
        GEMM_PIPE(4, (*(const bf16x8*)(&sH1[rt * 16 + l16][u * 32 + lg * 8])), B0, B1, a2)
    }
    // epi2 -> sH2 (packed)
    #pragma unroll
    for (int rt = 0; rt < 3; ++rt)
        #pragma unroll
        for (int i = 0; i < 4; ++i) {
            int row = rt * 16 + lg * 4 + i;
            bf16 v0 = (bf16)gelu_f(a2[rt][0][i] + b12v0);
            bf16 v1 = (bf16)gelu_f(a2[rt][1][i] + b12v1);
            PACK_STORE(sH2, row, pcol, v0, v1)
        }
    __syncthreads();   // sH2 visible; sH1 dead -> sP overlay safe after this

    // ---- G3: A=sH2 (phi), B=W13T (k-permuted) ----
    f32x4 a3[3][2];
    #pragma unroll
    for (int rt = 0; rt < 3; ++rt)
        #pragma unroll
        for (int c2 = 0; c2 < 2; ++c2) a3[rt][c2] = (f32x4){0.f, 0.f, 0.f, 0.f};
    {
        const bf16* B0 = ws + 163840 + (size_t)col0 * 128 + lg * 8;
        const bf16* B1 = ws + 163840 + (size_t)col1 * 128 + lg * 8;
        GEMM_PIPE(4, (*(const bf16x8*)(&sH2[rt * 16 + l16][u * 32 + lg * 8])), B0, B1, a3)
    }

    // epi3: v = m3 + b13 + hE ; per-row partial moments in-register
    float s1r[3][4], s2r[3][4];
    #pragma unroll
    for (int rt = 0; rt < 3; ++rt)
        #pragma unroll
        for (int i = 0; i < 4; ++i) { s1r[rt][i] = 0.f; s2r[rt][i] = 0.f; }
    #pragma unroll
    for (int c2 = 0; c2 < 2; ++c2) {
        float bb = c2 ? b13v1 : b13v0;
        #pragma unroll
        for (int rt = 0; rt < 3; ++rt)
            #pragma unroll
            for (int i = 0; i < 4; ++i) {
                float v = a3[rt][c2][i] + bb + rv[rt][c2][i];
                a3[rt][c2][i] = v;
                s1r[rt][i] += v; s2r[rt][i] += v * v;
            }
    }
    #pragma unroll
    for (int mseg = 1; mseg < 16; mseg <<= 1)
        #pragma unroll
        for (int rt = 0; rt < 3; ++rt)
            #pragma unroll
            for (int i = 0; i < 4; ++i) {
                s1r[rt][i] += __shfl_xor(s1r[rt][i], mseg);
                s2r[rt][i] += __shfl_xor(s2r[rt][i], mseg);
            }
    if (l16 == 0) {
        #pragma unroll
        for (int rt = 0; rt < 3; ++rt)
            #pragma unroll
            for (int i = 0; i < 4; ++i) {
                int row = rt * 16 + lg * 4 + i;
                sP1[row][w] = s1r[rt][i];
                sP2[row][w] = s2r[rt][i];
            }
    }
    __syncthreads();

    // finalize LN3 + store
    #pragma unroll
    for (int rt = 0; rt < 3; ++rt)
        #pragma unroll
        for (int i = 0; i < 4; ++i) {
            int row = rt * 16 + lg * 4 + i;
            f32x4 p1 = *(const f32x4*)sP1[row];
            f32x4 p2 = *(const f32x4*)sP2[row];
            float s1 = p1[0] + p1[1] + p1[2] + p1[3];
            float s2 = p2[0] + p2[1] + p2[2] + p2[3];
            float mn = s1 * (1.f / 128.f);
            float rs = rsqrtf(s2 * (1.f / 128.f) - mn * mn + EPSF);
            size_t rb = ((size_t)n * 48 + row) * H;
            outE[rb + col0] = (a3[rt][0][i] - mn) * rs * g3v0 + be3v0;
            outE[rb + col1] = (a3[rt][1][i] - mn) * rs * g3v1 + be3v1;
        }
}

extern "C" void kernel_launch(void* const* d_in, const int* in_sizes, int n_in,
                              void* d_out, int out_size, void* d_ws, size_t ws_size,
                              hipStream_t stream)
{
    const float* hV    = (const float*)d_in[0];
    const float* hVa   = (const float*)d_in[1];
    const float* hE    = (const float*)d_in[2];
    const float* W1    = (const float*)d_in[3];
    const float* b1    = (const float*)d_in[4];
    const float* W2    = (const float*)d_in[5];
    const float* b2    = (const float*)d_in[6];
    const float* W3    = (const float*)d_in[7];
    const float* b3    = (const float*)d_in[8];
    const float* W11   = (const float*)d_in[9];
    const float* b11   = (const float*)d_in[10];
    const float* W12   = (const float*)d_in[11];
    const float* b12   = (const float*)d_in[12];
    const float* W13   = (const float*)d_in[13];
    const float* b13   = (const float*)d_in[14];
    const float* Win   = (const float*)d_in[15];
    const float* b_in  = (const float*)d_in[16];
    const float* Wout  = (const float*)d_in[17];
    const float* b_out = (const float*)d_in[18];
    const float* g1    = (const float*)d_in[19];
    const float* be1   = (const float*)d_in[20];
    const float* g2    = (const float*)d_in[21];
    const float* be2   = (const float*)d_in[22];
    const float* g3    = (const float*)d_in[23];
    const float* be3   = (const float*)d_in[24];
    const float* maskV = (const float*)d_in[25];
    const float* maskA = (const float*)d_in[26];
    const int*   Eidx  = (const int*)  d_in[27];

    bf16*  ws   = (bf16*)d_ws;
    float* wsf  = (float*)d_ws;
    float* outV = (float*)d_out;
    float* outE = outV + (size_t)BB * NN * H;

    prep_weights<<<1216, 256, 0, stream>>>(W1, W2, W3, W11, W12, W13, Win, Wout, ws);
    u1_kernel<<<32, 512, 0, stream>>>(hV, hVa, b1, ws, wsf);
    node_msg_kernel<<<BB * NN, 256, 0, stream>>>(hV, hE, b2, b3, g1, be1, maskA, Eidx, ws, wsf);
    ffn_kernel<<<BB * NN / 32, 512, 0, stream>>>(b_in, b_out, b11, g2, be2, maskV, ws, wsf, outV);
    edge_kernel<<<BB * NN, 256, 0, stream>>>(hE, b12, b13, g3, be3, Eidx, ws, wsf, outE);
}